// Round 7
// baseline (949.811 us; speedup 1.0000x reference)
//
#include <hip/hip_runtime.h>

typedef short v8s __attribute__((ext_vector_type(8)));
typedef float v4f __attribute__((ext_vector_type(4)));

// problem constants
#define NCH    64
#define NHH    128
#define NWW    128
#define NOC    64
#define KSTEPS 18          // 576 / 32

// LDS x-slab: [4 rows][66 cols][72 c (64 + 8 pad)] bf16
#define CSTR 72
#define COLS 66
#define SLAB_BYTES (4 * COLS * CSTR * 2)     // 38016
#define RING_OFF   SLAB_BYTES
#define SLOT_BYTES 4096                      // one k-step of B, all 64 oc
#define RING_WAVE_BYTES (3 * SLOT_BYTES)     // 12288
#define SMEM_BYTES (SLAB_BYTES + 8 * RING_WAVE_BYTES)  // 136320 <= 160 KiB
#define OSTR 65                              // otile col-stride (bank-spread)

__device__ __forceinline__ unsigned short f2bf(float f) {
  unsigned int u = __float_as_uint(f);
  u += 0x7FFFu + ((u >> 16) & 1u);           // round-to-nearest-even
  return (unsigned short)(u >> 16);
}

// ---------------------------------------------------------------------------
// Pack expert weights into MFMA B-fragment-linear bf16:
// f = (((e*18+s)*4 + nt)*64 + lane)*8 + j
//   = W[e][k = s*32+(lane>>4)*8+j][n = nt*16+(lane&15)]
// with k = (kh*3+kw)*64 + c and W[e][k][n] = expert_w[e][n][c][kh][kw].
// One (e,s) slice = 4096 contiguous bytes. Total elements: 294912.
// ---------------------------------------------------------------------------
__global__ void pack_b_kernel(const float* __restrict__ ew,
                              unsigned short* __restrict__ bp) {
  int f = blockIdx.x * 256 + threadIdx.x;    // 0 .. 294911
  int j = f & 7;
  int t = f >> 3;
  int lane = t & 63;
  t >>= 6;
  int nt = t & 3;
  t >>= 2;                                   // t = e*18 + s
  int s = t % KSTEPS;
  int e = t / KSTEPS;
  int k = s * 32 + (lane >> 4) * 8 + j;
  int n = nt * 16 + (lane & 15);
  bp[f] = f2bf(ew[((e * NOC + n) * NCH + (k & 63)) * 9 + (k >> 6)]);
}

// ---------------------------------------------------------------------------
// Gating: block = (b-quad, ph, pw): 4 batches share the gw float4 loads.
// fp32 dot + softmax. 3-level shuffle + LDS finish for the reduction.
// ---------------------------------------------------------------------------
__global__ void gate_kernel(const float* __restrict__ x,
                            const float* __restrict__ gw,
                            const float* __restrict__ gb,
                            float* __restrict__ gate_out) {
  int pid = blockIdx.x;                 // 0..1023
  int pw = pid & 15;
  int ph = (pid >> 4) & 15;
  int bq = pid >> 8;                    // batch quad 0..3
  int tid = threadIdx.x;

  float cy = (ph + 0.5f) / 16.0f;
  float cx = (pw + 0.5f) / 16.0f;

  float acc[4][8];
#pragma unroll
  for (int bb = 0; bb < 4; ++bb)
#pragma unroll
    for (int e = 0; e < 8; ++e) acc[bb][e] = 0.f;

  // image part: 64 ch x 16 float4 groups = 1024 units; gw shared by 4 batches
  for (int u = tid; u < 1024; u += 256) {
    int ch = u >> 4;
    int pix = (u & 15) * 4;
    int py = pix >> 3;
    int px = pix & 7;
    float4 wv[8];
#pragma unroll
    for (int e = 0; e < 8; ++e)
      wv[e] = *(const float4*)&gw[e * 6144 + ch * 64 + pix];
#pragma unroll
    for (int bb = 0; bb < 4; ++bb) {
      const float4 xv = *(const float4*)&x[(((bq * 4 + bb) * NCH + ch) * NHH + ph * 8 + py) * NWW + pw * 8 + px];
#pragma unroll
      for (int e = 0; e < 8; ++e)
        acc[bb][e] += xv.x * wv[e].x + xv.y * wv[e].y + xv.z * wv[e].z + xv.w * wv[e].w;
    }
  }
  // positional part: constant over the 64 patch pixels and over batches
  for (int u = tid; u < 512; u += 256) {
    int j = u >> 4;
    int g4 = (u & 15) * 4;
    float freq = (float)(1 << (j & 7)) * 3.14159265358979323846f;
    float base = (j < 16) ? cy : cx;
    float a = base * freq;
    float v = ((j >> 3) & 1) ? cosf(a) : sinf(a);
#pragma unroll
    for (int e = 0; e < 8; ++e) {
      const float4 wv = *(const float4*)&gw[e * 6144 + 4096 + j * 64 + g4];
      float s = v * (wv.x + wv.y + wv.z + wv.w);
#pragma unroll
      for (int bb = 0; bb < 4; ++bb) acc[bb][e] += s;
    }
  }

  // 3-level shuffle: lanes 0..7 hold partials over {l, l+8, ..., l+56}
#pragma unroll
  for (int bb = 0; bb < 4; ++bb)
#pragma unroll
    for (int e = 0; e < 8; ++e) {
      float a = acc[bb][e];
      a += __shfl_down(a, 32, 64);
      a += __shfl_down(a, 16, 64);
      a += __shfl_down(a, 8, 64);
      acc[bb][e] = a;
    }

  __shared__ float red[4][4][8][8];   // [wave][bb][e][lane 0..7]
  __shared__ float lg[4][8];
  int wid = tid >> 6;
  int lane = tid & 63;
  if (lane < 8) {
#pragma unroll
    for (int bb = 0; bb < 4; ++bb)
#pragma unroll
      for (int e = 0; e < 8; ++e) red[wid][bb][e][lane] = acc[bb][e];
  }
  __syncthreads();
  if (tid < 32) {
    int bb = tid >> 3, e = tid & 7;
    float s = gb[e];
#pragma unroll
    for (int w = 0; w < 4; ++w)
#pragma unroll
      for (int l = 0; l < 8; ++l) s += red[w][bb][e][l];
    lg[bb][e] = s;
  }
  __syncthreads();
  if (tid < 4) {
    float mx = -1e30f;
#pragma unroll
    for (int e = 0; e < 8; ++e) mx = fmaxf(mx, lg[tid][e]);
    float ex[8], sum = 0.f;
#pragma unroll
    for (int e = 0; e < 8; ++e) { ex[e] = expf(lg[tid][e] - mx); sum += ex[e]; }
    float inv = 1.0f / sum;
    int b = bq * 4 + tid;
#pragma unroll
    for (int e = 0; e < 8; ++e)
      gate_out[((b * 16 + ph) * 16 + pw) * 8 + e] = ex[e] * inv;
  }
}

__device__ __forceinline__ void dma16(const char* gsrc, char* ldst) {
  __builtin_amdgcn_global_load_lds(
      (const __attribute__((address_space(1))) void*)gsrc,
      (__attribute__((address_space(3))) void*)ldst, 16, 0, 0);
}

// ---------------------------------------------------------------------------
// Main fused kernel: block = 8 waves (512 thr) = 8 experts, ALL sharing one
// M=128 (2 rows x 64 cols) x N=64 (all oc) output tile. Each wave computes
// its expert's conv tile in regs (vacc 128, NO persistent oacc), then
// bias+relu+gate and ds-atomic-adds into a shared LDS fp32 tile (overlaid on
// the x-slab). B: per-wave 3-slot LDS ring (global_load_lds, vmcnt pacing,
// no K-loop barriers). 42.7 FLOP per LDS byte (vs 25.6 in R6).
// ---------------------------------------------------------------------------
__global__ __launch_bounds__(512, 2) void moe_conv_kernel(
    const float* __restrict__ x,
    const float* __restrict__ eb,
    const unsigned short* __restrict__ bp,
    const float* __restrict__ gate,
    float* __restrict__ out) {
  __shared__ __align__(16) char smem[SMEM_BYTES];
  unsigned short* slab = (unsigned short*)smem;

  const int tid = threadIdx.x;
  const int bid = blockIdx.x;
  const int wseg = bid & 1;
  const int hp = (bid >> 1) & 63;     // output row pair
  const int b = bid >> 7;
  const int w0 = wseg * 64;
  const int wid = tid >> 6;           // wave = expert
  const int lane = tid & 63;
  const int quad = lane >> 4;
  const int l15 = lane & 15;
  const int e = wid;

  char* ringbase = smem + RING_OFF + wid * RING_WAVE_BYTES;
  const char* bbase = (const char*)bp + e * (KSTEPS * SLOT_BYTES);

  // gate for this block's 8 patches, lane-spread (lane&7 = patch)
  const float gl = gate[((b * 16 + (hp >> 2)) * 16 + wseg * 8 + (lane & 7)) * 8 + e];
  float bias[4];
#pragma unroll
  for (int nt = 0; nt < 4; ++nt) bias[nt] = eb[e * NOC + nt * 16 + l15];

  // prologue: ring slots 0..2 (12 granules), drained by the barrier below
#pragma unroll
  for (int t = 0; t < 3; ++t) {
    const char* gsrc = bbase + t * SLOT_BYTES + lane * 16;
    char* ldst = ringbase + t * SLOT_BYTES;
#pragma unroll
    for (int g = 0; g < 4; ++g) dma16(gsrc + g * 1024, ldst + g * 1024);
  }

  // --- stage x slab: rows hp*2-1 .. hp*2+2, cols w0-1 .. w0+64, all c ---
  const int hbase = hp * 2 - 1;
  const int wbase = w0 - 1;
  for (int flat = tid; flat < 4 * 32 * COLS; flat += 512) {
    int col = flat % COLS;
    int t = flat / COLS;
    int cp = t & 31;                    // channel pair
    int r = t >> 5;                     // slab row 0..3
    int gh = hbase + r;
    int gw_ = wbase + col;
    float v0 = 0.f, v1 = 0.f;
    if (((unsigned)gh < 128u) && ((unsigned)gw_ < 128u)) {
      const float* px = x + (((b * NCH + cp * 2) * NHH + gh) * NWW + gw_);
      v0 = px[0];
      v1 = px[NHH * NWW];
    }
    unsigned int pk = (unsigned int)f2bf(v0) | ((unsigned int)f2bf(v1) << 16);
    *(unsigned int*)&slab[(r * COLS + col) * CSTR + cp * 2] = pk;
  }
  __syncthreads();    // slab + prologue B landed (single vmcnt(0) drain)

  const v4f vzero = {0.f, 0.f, 0.f, 0.f};
  v4f vacc[8][4];
#pragma unroll
  for (int mt = 0; mt < 8; ++mt)
#pragma unroll
    for (int nt = 0; nt < 4; ++nt) vacc[mt][nt] = vzero;

  // wave-constant part of the A-frag LDS address
  const unsigned short* abase = &slab[l15 * CSTR + quad * 8];

#pragma unroll
  for (int s = 0; s < KSTEPS; ++s) {
    // 3 steps x 4 granules outstanding; <=8 left  =>  this step's 4 landed
    asm volatile("s_waitcnt vmcnt(8)" ::: "memory");

    const unsigned short* bslot = (const unsigned short*)(ringbase + (s % 3) * SLOT_BYTES);
    v8s bf[4];
#pragma unroll
    for (int nt = 0; nt < 4; ++nt)
      bf[nt] = *(const v8s*)(bslot + nt * 512 + lane * 8);

    const int kh = s / 6;
    const int kw = (s / 2) % 3;
    const int ch = s & 1;
    v8s af[8];
#pragma unroll
    for (int mt = 0; mt < 8; ++mt)
      af[mt] = *(const v8s*)(abase +
          (((mt >> 2) + kh) * COLS + (mt & 3) * 16 + kw) * CSTR + ch * 32);

#pragma unroll
    for (int mt = 0; mt < 8; ++mt)
#pragma unroll
      for (int nt = 0; nt < 4; ++nt)
        vacc[mt][nt] = __builtin_amdgcn_mfma_f32_16x16x32_bf16(af[mt], bf[nt], vacc[mt][nt], 0, 0, 0);

    // slot (s%3) consumed (drain LDS reads), refill with step s+3
    asm volatile("s_waitcnt lgkmcnt(0)" ::: "memory");
    int t3 = s + 3;
    if (t3 > 17) t3 = 17;               // harmless dup at tail, keeps FIFO math
    const char* gsrc = bbase + t3 * SLOT_BYTES + lane * 16;
    char* ldst = ringbase + (s % 3) * SLOT_BYTES;
#pragma unroll
    for (int g = 0; g < 4; ++g) dma16(gsrc + g * 1024, ldst + g * 1024);
  }

  // ---- combine: gated relu into shared LDS fp32 tile (overlays slab) ----
  asm volatile("s_waitcnt vmcnt(0)" ::: "memory");
  __syncthreads();                      // all slab reads done
  float* otile = (float*)smem;          // [row 2][oc 64][col OSTR] = 33280 B
  for (int i = tid; i < 2 * 64 * OSTR; i += 512) otile[i] = 0.f;
  __syncthreads();

#pragma unroll
  for (int mt = 0; mt < 8; ++mt) {
    const float g = __shfl(gl, (mt & 3) * 2 + (quad >> 1), 64);
    const int row = mt >> 2;
    const int colb = (mt & 3) * 16 + quad * 4;
#pragma unroll
    for (int nt = 0; nt < 4; ++nt) {
      const int oc = nt * 16 + l15;
      float* obase = &otile[(row * 64 + oc) * OSTR + colb];
#pragma unroll
      for (int r = 0; r < 4; ++r) {
        float v = fmaxf(vacc[mt][nt][r] + bias[nt], 0.f) * g;
        atomicAdd(obase + r, v);
      }
    }
  }
  __syncthreads();

  // ---- store: wave w -> oc w*8..w*8+7, full 256 B rows, coalesced ----
  const int h0 = hp * 2;
#pragma unroll
  for (int r2 = 0; r2 < 2; ++r2) {
#pragma unroll
    for (int k = 0; k < 8; ++k) {
      const int oc = wid * 8 + k;
      out[((b * NOC + oc) * NHH + h0 + r2) * NWW + w0 + lane] =
          otile[(r2 * 64 + oc) * OSTR + lane];
    }
  }
}

// ---------------------------------------------------------------------------
extern "C" void kernel_launch(void* const* d_in, const int* in_sizes, int n_in,
                              void* d_out, int out_size, void* d_ws, size_t ws_size,
                              hipStream_t stream) {
  const float* x  = (const float*)d_in[0];
  const float* ew = (const float*)d_in[1];
  const float* eb = (const float*)d_in[2];
  const float* gw = (const float*)d_in[3];
  const float* gb = (const float*)d_in[4];
  float* out = (float*)d_out;

  unsigned short* bp = (unsigned short*)d_ws;              // 294912 bf16 = 589824 B
  float* gate = (float*)((char*)d_ws + 589824);            // 4096*8 fp32 = 131072 B

  hipLaunchKernelGGL(pack_b_kernel, dim3(1152), dim3(256), 0, stream, ew, bp);
  hipLaunchKernelGGL(gate_kernel, dim3(1024), dim3(256), 0, stream, x, gw, gb, gate);
  hipLaunchKernelGGL(moe_conv_kernel, dim3(2048), dim3(512), 0, stream, x, eb, bp, gate, out);
}